// Round 8
// baseline (77.838 us; speedup 1.0000x reference)
//
#include <hip/hip_runtime.h>
#include <stdint.h>

typedef __attribute__((ext_vector_type(8))) short short8;
typedef __attribute__((ext_vector_type(4))) float f32x4;

__device__ __forceinline__ unsigned short f2bf(float f) {
  union { float f; uint32_t u; } v; v.f = f;
  uint32_t u = v.u;
  uint32_t r = (u + 0x7FFFu + ((u >> 16) & 1u)) >> 16;
  return (unsigned short)r;
}
__device__ __forceinline__ float bf2f(unsigned short h) {
  union { uint32_t u; float f; } v; v.u = ((uint32_t)h) << 16; return v.f;
}

// ============================================================================
// Phase 1: U[i] = bf16(src_emb[i] @ W1[:128] + b1); V[j] = bf16(dst_emb[j] @ W1[128:])
// Grid-stride 64-row tiles; register-prefetch pipeline; packed dword C stores.
// ============================================================================
#define NBM 64
__global__ __launch_bounds__(256, 4)
void node_phase_kernel(const float* __restrict__ src_emb,
                       const float* __restrict__ dst_emb,
                       const float* __restrict__ W1,
                       const float* __restrict__ b1,
                       unsigned short* __restrict__ UV,
                       int Nn, int ntiles) {
  __shared__ __align__(16) char Als[NBM * 256];   // 64 rows x 128 bf16, 16 KB

  const int tbl = blockIdx.y;
  const float* emb = tbl ? dst_emb : src_emb;
  const float* Wt  = W1 + (size_t)tbl * 128 * 128;
  unsigned short* outp = UV + (size_t)tbl * Nn * 128;

  const int tid  = threadIdx.x;
  const int lane = tid & 63;
  const int w    = tid >> 6;
  const int l15  = lane & 15;
  const int lk8  = (lane >> 4) * 8;

  // B fragments, ADJACENT-col mapping: frag nf col = w*32 + 2*l15 + nf.
  short8 bfrag[4][2];
#pragma unroll
  for (int s = 0; s < 4; ++s) {
#pragma unroll
    for (int nf = 0; nf < 2; ++nf) {
      const int col = w * 32 + 2 * l15 + nf;
      short8 t;
#pragma unroll
      for (int j = 0; j < 8; ++j) {
        const int k = s * 32 + lk8 + j;
        t[j] = (short)f2bf(Wt[k * 128 + col]);
      }
      bfrag[s][nf] = t;
    }
  }
  const int colb = w * 32 + 2 * l15;
  const float bias0 = tbl ? 0.f : b1[colb];
  const float bias1 = tbl ? 0.f : b1[colb + 1];

  const int q = tid & 15, r0 = tid >> 4;
  const int swz = (l15 & 7) << 4;
  const int gx = gridDim.x;

  float4 p0[4], p1[4];
#pragma unroll
  for (int i = 0; i < 4; ++i) {
    const int node = blockIdx.x * NBM + i * 16 + r0;
    if (node < Nn) {
      const float* base = emb + (size_t)node * 128 + q * 8;
      p0[i] = *(const float4*)base;
      p1[i] = *(const float4*)(base + 4);
    }
  }

  for (int t = blockIdx.x; t < ntiles; t += gx) {
    const int t0 = t * NBM;

#pragma unroll
    for (int i = 0; i < 4; ++i) {
      const int row = i * 16 + r0;
      short8 hv;
      hv[0] = (short)f2bf(p0[i].x); hv[1] = (short)f2bf(p0[i].y);
      hv[2] = (short)f2bf(p0[i].z); hv[3] = (short)f2bf(p0[i].w);
      hv[4] = (short)f2bf(p1[i].x); hv[5] = (short)f2bf(p1[i].y);
      hv[6] = (short)f2bf(p1[i].z); hv[7] = (short)f2bf(p1[i].w);
      const int byteoff = row * 256 + ((q * 16) ^ ((row & 7) << 4));
      *(short8*)(Als + byteoff) = hv;
    }
    __syncthreads();

    const int tn = t + gx;
    if (tn < ntiles) {
#pragma unroll
      for (int i = 0; i < 4; ++i) {
        const int node = tn * NBM + i * 16 + r0;
        if (node < Nn) {
          const float* base = emb + (size_t)node * 128 + q * 8;
          p0[i] = *(const float4*)base;
          p1[i] = *(const float4*)(base + 4);
        }
      }
    }

#pragma unroll
    for (int m = 0; m < 4; ++m) {
      f32x4 acc0 = {0.f, 0.f, 0.f, 0.f};
      f32x4 acc1 = {0.f, 0.f, 0.f, 0.f};
      const int rowb = (m * 16 + l15) * 256;
      const int kb0  = lk8 * 2;
#pragma unroll
      for (int s = 0; s < 4; ++s) {
        const int off = rowb + ((s * 64 + kb0) ^ swz);
        const short8 a = *(const short8*)(Als + off);
        acc0 = __builtin_amdgcn_mfma_f32_16x16x32_bf16(a, bfrag[s][0], acc0, 0, 0, 0);
        acc1 = __builtin_amdgcn_mfma_f32_16x16x32_bf16(a, bfrag[s][1], acc1, 0, 0, 0);
      }
#pragma unroll
      for (int reg = 0; reg < 4; ++reg) {
        const int orow = t0 + m * 16 + ((lane >> 4) * 4) + reg;
        if (orow < Nn) {
          const uint32_t pk = (uint32_t)f2bf(acc0[reg] + bias0) |
                              ((uint32_t)f2bf(acc1[reg] + bias1) << 16);
          *(uint32_t*)&outp[(size_t)orow * 128 + colb] = pk;
        }
      }
    }
    __syncthreads();
  }
}

// ============================================================================
// Phase 2: out[e] = sigmoid( sum_c relu(U[s][c]+V[d][c]) * W2[c] + b2 )
// 16 lanes/edge. Contiguous 16-edge chunk per subgroup; idx batch loaded
// coalesced ONCE per chunk and broadcast per-iteration via __shfl (no idx
// load in the loop -> no vmcnt drain). u/v ping-pong fully unrolled: loads
// for k+1 in flight under compute of k. Next chunk's idx double-buffered.
// ============================================================================
#define LOAD_ROWS(sreg, dreg, KK, su, sv)                                      \
  {                                                                            \
    const uint32_t _s = (uint32_t)__shfl(sreg, (KK), 16);                      \
    const uint32_t _d = (uint32_t)__shfl(dreg, (KK), 16);                      \
    su = *(const short8*)(U + (size_t)_s * 128 + l15 * 8);                     \
    sv = *(const short8*)(V + (size_t)_d * 128 + l15 * 8);                     \
  }

#define COMPUTE_E(KK, su, sv)                                                  \
  {                                                                            \
    float _acc = 0.f;                                                          \
    _Pragma("unroll") for (int _c = 0; _c < 8; ++_c) {                         \
      float _g = bf2f((unsigned short)su[_c]) + bf2f((unsigned short)sv[_c]);  \
      _g = _g > 0.f ? _g : 0.f;                                                \
      _acc = fmaf(_g, w2s[_c], _acc);                                          \
    }                                                                          \
    _acc += __shfl_xor(_acc, 1, 16);                                           \
    _acc += __shfl_xor(_acc, 2, 16);                                           \
    _acc += __shfl_xor(_acc, 4, 16);                                           \
    _acc += __shfl_xor(_acc, 8, 16);                                           \
    if (l15 == 0) {                                                            \
      const int _e = ebase_sg + (KK);                                          \
      if (_e < E) out[_e] = 1.f / (1.f + __expf(-(_acc + b2s)));               \
    }                                                                          \
  }

__global__ __launch_bounds__(256, 8)
void edge_phase_kernel(const unsigned short* __restrict__ UV,
                       const int* __restrict__ eidx,
                       const float* __restrict__ W2,
                       const float* __restrict__ b2,
                       float* __restrict__ out,
                       int E, int Nn) {
  const int tid = threadIdx.x;
  const int l15 = tid & 15;

  float w2s[8];
#pragma unroll
  for (int j = 0; j < 8; ++j) w2s[j] = W2[l15 * 8 + j];
  const float b2s = b2[0];
  const unsigned short* U = UV;
  const unsigned short* V = UV + (size_t)Nn * 128;

  const int gstep = gridDim.x * 256;       // edges per grid sweep
  int base = blockIdx.x * 256;             // this block's chunk base
  if (base >= E) return;

  // ---- load chunk 0's idx batch (lane tid holds edge base+tid's indices) --
  int eb0 = base + tid; eb0 = eb0 < E ? eb0 : E - 1;
  int sidxA = eidx[eb0];
  int didxA = eidx[E + eb0];
  int sidxB, didxB;

  short8 uA, vA, uB, vB;
  // prologue: k=0 rows of chunk 0
  {
    int ebase_sg_dummy; (void)ebase_sg_dummy;
    const uint32_t _s = (uint32_t)__shfl(sidxA, 0, 16);
    const uint32_t _d = (uint32_t)__shfl(didxA, 0, 16);
    uA = *(const short8*)(U + (size_t)_s * 128 + l15 * 8);
    vA = *(const short8*)(V + (size_t)_d * 128 + l15 * 8);
  }

  for (;;) {
    const int ebase_sg = base + (tid & 0xF0);   // this subgroup's 16-edge run
    const int nbase = base + gstep;

    // issue NEXT chunk's idx loads first (oldest outstanding -> never stalls)
    {
      int ebn = nbase + tid; ebn = ebn < E ? ebn : E - 1;
      sidxB = eidx[ebn];
      didxB = eidx[E + ebn];
    }

#pragma unroll
    for (int k2 = 0; k2 < 8; ++k2) {
      const int k = 2 * k2;
      LOAD_ROWS(sidxA, didxA, k + 1, uB, vB);        // prefetch k+1
      COMPUTE_E(k, uA, vA);                          // compute k
      if (k2 < 7) {
        LOAD_ROWS(sidxA, didxA, k + 2, uA, vA);      // prefetch k+2
      } else if (nbase < E) {
        // prefetch next chunk's k=0 (idxB completed long ago in vmcnt order)
        const uint32_t _s = (uint32_t)__shfl(sidxB, 0, 16);
        const uint32_t _d = (uint32_t)__shfl(didxB, 0, 16);
        uA = *(const short8*)(U + (size_t)_s * 128 + l15 * 8);
        vA = *(const short8*)(V + (size_t)_d * 128 + l15 * 8);
      }
      COMPUTE_E(k + 1, uB, vB);                      // compute k+1
    }

    if (nbase >= E) break;
    base = nbase;
    sidxA = sidxB;
    didxA = didxB;
  }
}

// ============================================================================
// Fallback (proven R2 kernel): fused gather+MFMA, used if ws_size too small.
// ============================================================================
#define BM 64
__global__ __launch_bounds__(256, 4)
void edge_decoder_fused(const float* __restrict__ src_emb,
                        const float* __restrict__ dst_emb,
                        const int* __restrict__ eidx,
                        const float* __restrict__ W1,
                        const float* __restrict__ b1,
                        const float* __restrict__ W2,
                        const float* __restrict__ b2,
                        float* __restrict__ out,
                        int E, int ntiles) {
  __shared__ __align__(16) char Als[BM * 512];
  __shared__ float rowpart[4][BM];

  const int tid  = threadIdx.x;
  const int lane = tid & 63;
  const int w    = tid >> 6;
  const int l15  = lane & 15;
  const int lk8  = (lane >> 4) * 8;

  short8 bfrag[8][2];
#pragma unroll
  for (int s = 0; s < 8; ++s) {
#pragma unroll
    for (int nf = 0; nf < 2; ++nf) {
      const int col = w * 32 + nf * 16 + l15;
      short8 t;
#pragma unroll
      for (int j = 0; j < 8; ++j) {
        const int k = s * 32 + lk8 + j;
        t[j] = (short)f2bf(W1[k * 128 + col]);
      }
      bfrag[s][nf] = t;
    }
  }
  float b1v[2], w2v[2];
#pragma unroll
  for (int nf = 0; nf < 2; ++nf) {
    const int col = w * 32 + nf * 16 + l15;
    b1v[nf] = b1[col];
    w2v[nf] = W2[col];
  }
  const float b2s = b2[0];

  const int q  = tid & 31;
  const int r0 = tid >> 5;
  const int qq = q & 15;
  const bool is_src = (q < 16);
  const int swz = (l15 & 7) << 4;

  for (int t = blockIdx.x; t < ntiles; t += gridDim.x) {
    const int t0 = t * BM;
#pragma unroll
    for (int i = 0; i < 8; ++i) {
      const int row = i * 8 + r0;
      const int e = t0 + row;
      if (e < E) {
        const int node = is_src ? eidx[e] : eidx[E + e];
        const float* base = (is_src ? src_emb : dst_emb) + (size_t)node * 128 + qq * 8;
        const float4 f0 = *(const float4*)base;
        const float4 f1 = *(const float4*)(base + 4);
        short8 hv;
        hv[0] = (short)f2bf(f0.x); hv[1] = (short)f2bf(f0.y);
        hv[2] = (short)f2bf(f0.z); hv[3] = (short)f2bf(f0.w);
        hv[4] = (short)f2bf(f1.x); hv[5] = (short)f2bf(f1.y);
        hv[6] = (short)f2bf(f1.z); hv[7] = (short)f2bf(f1.w);
        const int byteoff = row * 512 + ((q * 16) ^ ((row & 7) << 4));
        *(short8*)(Als + byteoff) = hv;
      }
    }
    __syncthreads();

    for (int m = 0; m < 4; ++m) {
      f32x4 acc0 = {0.f, 0.f, 0.f, 0.f};
      f32x4 acc1 = {0.f, 0.f, 0.f, 0.f};
      const int rowb = (m * 16 + l15) * 512;
      const int kb0  = lk8 * 2;
#pragma unroll
      for (int s = 0; s < 8; ++s) {
        const int off = rowb + ((s * 64 + kb0) ^ swz);
        const short8 a = *(const short8*)(Als + off);
        acc0 = __builtin_amdgcn_mfma_f32_16x16x32_bf16(a, bfrag[s][0], acc0, 0, 0, 0);
        acc1 = __builtin_amdgcn_mfma_f32_16x16x32_bf16(a, bfrag[s][1], acc1, 0, 0, 0);
      }
      float pr[4];
#pragma unroll
      for (int reg = 0; reg < 4; ++reg) {
        float h0 = acc0[reg] + b1v[0]; h0 = h0 > 0.f ? h0 : 0.f;
        float h1 = acc1[reg] + b1v[1]; h1 = h1 > 0.f ? h1 : 0.f;
        pr[reg] = h0 * w2v[0] + h1 * w2v[1];
      }
#pragma unroll
      for (int off = 1; off < 16; off <<= 1) {
#pragma unroll
        for (int reg = 0; reg < 4; ++reg)
          pr[reg] += __shfl_xor(pr[reg], off, 64);
      }
      if (l15 == 0) {
        const int rbase = m * 16 + (lane >> 4) * 4;
#pragma unroll
        for (int reg = 0; reg < 4; ++reg)
          rowpart[w][rbase + reg] = pr[reg];
      }
    }
    __syncthreads();

    if (tid < BM) {
      const int e = t0 + tid;
      if (e < E) {
        const float sum = rowpart[0][tid] + rowpart[1][tid] +
                          rowpart[2][tid] + rowpart[3][tid] + b2s;
        out[e] = 1.f / (1.f + __expf(-sum));
      }
    }
    __syncthreads();
  }
}

extern "C" void kernel_launch(void* const* d_in, const int* in_sizes, int n_in,
                              void* d_out, int out_size, void* d_ws, size_t ws_size,
                              hipStream_t stream) {
  const float* src = (const float*)d_in[0];
  const float* dst = (const float*)d_in[1];
  const int*   eix = (const int*)d_in[2];
  const float* W1  = (const float*)d_in[3];
  const float* b1  = (const float*)d_in[4];
  const float* W2  = (const float*)d_in[5];
  const float* b2  = (const float*)d_in[6];
  float* out = (float*)d_out;

  const int E  = in_sizes[2] / 2;
  const int Nn = in_sizes[0] / 128;
  const size_t uv_bytes = (size_t)Nn * 128 * 2 * sizeof(unsigned short);

  if (ws_size >= uv_bytes) {
    unsigned short* UV = (unsigned short*)d_ws;
    const int ntiles_n = (Nn + NBM - 1) / NBM;
    const int gx = ntiles_n < 512 ? ntiles_n : 512;
    node_phase_kernel<<<dim3(gx, 2), 256, 0, stream>>>(src, dst, W1, b1, UV, Nn, ntiles_n);
    const int nchunks = (E + 255) / 256;
    const int nblk = nchunks < 2048 ? nchunks : 2048;
    edge_phase_kernel<<<nblk, 256, 0, stream>>>(UV, eix, W2, b2, out, E, Nn);
  } else {
    const int ntiles = (E + BM - 1) / BM;
    const int grid = ntiles < 2048 ? ntiles : 2048;
    edge_decoder_fused<<<grid, 256, 0, stream>>>(src, dst, eix, W1, b1, W2, b2,
                                                 out, E, ntiles);
  }
}

// Round 9
// 74.155 us; speedup vs baseline: 1.0497x; 1.0497x over previous
//
#include <hip/hip_runtime.h>
#include <stdint.h>

typedef __attribute__((ext_vector_type(8))) short short8;
typedef __attribute__((ext_vector_type(8))) signed char schar8;
typedef __attribute__((ext_vector_type(4))) float f32x4;

__device__ __forceinline__ unsigned short f2bf(float f) {
  union { float f; uint32_t u; } v; v.f = f;
  uint32_t u = v.u;
  uint32_t r = (u + 0x7FFFu + ((u >> 16) & 1u)) >> 16;
  return (unsigned short)r;
}
__device__ __forceinline__ float bf2f(unsigned short h) {
  union { uint32_t u; float f; } v; v.u = ((uint32_t)h) << 16; return v.f;
}

// ============================================================================
// Phase 1: h_u[i] = src_emb[i] @ W1[:128] + b1 ; h_v[j] = dst_emb[j] @ W1[128:]
// Quantized per-row to int8: Q[node][c] = rint(h*127/amax_row), SC[node]=amax/127.
// Grid-stride 64-row tiles; reg-prefetch pipeline; within-wave shfl absmax +
// 1KB LDS cross-wave partial exchange; 2-byte packed stores. gridDim.y = table.
// ============================================================================
#define NBM 64
__global__ __launch_bounds__(256, 4)
void node_phase_q8(const float* __restrict__ src_emb,
                   const float* __restrict__ dst_emb,
                   const float* __restrict__ W1,
                   const float* __restrict__ b1,
                   int8_t* __restrict__ Q,
                   float* __restrict__ SC,
                   int Nn, int ntiles) {
  __shared__ __align__(16) char Als[NBM * 256];     // 16 KB input tile
  __shared__ __align__(16) float pam[NBM][4];       // 1 KB per-wave |h| partials

  const int tbl = blockIdx.y;
  const float* emb = tbl ? dst_emb : src_emb;
  const float* Wt  = W1 + (size_t)tbl * 128 * 128;
  int8_t* Qt  = Q  + (size_t)tbl * Nn * 128;
  float*  SCt = SC + (size_t)tbl * Nn;

  const int tid  = threadIdx.x;
  const int lane = tid & 63;
  const int w    = tid >> 6;          // wave 0..3 -> cols [w*32, w*32+32)
  const int l15  = lane & 15;
  const int lk8  = (lane >> 4) * 8;

  // B fragments, ADJACENT-col mapping: frag nf col = w*32 + 2*l15 + nf.
  short8 bfrag[4][2];
#pragma unroll
  for (int s = 0; s < 4; ++s) {
#pragma unroll
    for (int nf = 0; nf < 2; ++nf) {
      const int col = w * 32 + 2 * l15 + nf;
      short8 t;
#pragma unroll
      for (int j = 0; j < 8; ++j) {
        const int k = s * 32 + lk8 + j;
        t[j] = (short)f2bf(Wt[k * 128 + col]);
      }
      bfrag[s][nf] = t;
    }
  }
  const int colb = w * 32 + 2 * l15;
  const float bias0 = tbl ? 0.f : b1[colb];
  const float bias1 = tbl ? 0.f : b1[colb + 1];

  const int q = tid & 15, r0 = tid >> 4;
  const int swz = (l15 & 7) << 4;
  const int gx = gridDim.x;

  float4 p0[4], p1[4];
#pragma unroll
  for (int i = 0; i < 4; ++i) {
    const int node = blockIdx.x * NBM + i * 16 + r0;
    if (node < Nn) {
      const float* base = emb + (size_t)node * 128 + q * 8;
      p0[i] = *(const float4*)base;
      p1[i] = *(const float4*)(base + 4);
    }
  }

  for (int t = blockIdx.x; t < ntiles; t += gx) {
    const int t0 = t * NBM;

    // ---- prefetched regs -> swizzled LDS ----
#pragma unroll
    for (int i = 0; i < 4; ++i) {
      const int row = i * 16 + r0;
      short8 hv;
      hv[0] = (short)f2bf(p0[i].x); hv[1] = (short)f2bf(p0[i].y);
      hv[2] = (short)f2bf(p0[i].z); hv[3] = (short)f2bf(p0[i].w);
      hv[4] = (short)f2bf(p1[i].x); hv[5] = (short)f2bf(p1[i].y);
      hv[6] = (short)f2bf(p1[i].z); hv[7] = (short)f2bf(p1[i].w);
      const int byteoff = row * 256 + ((q * 16) ^ ((row & 7) << 4));
      *(short8*)(Als + byteoff) = hv;
    }
    __syncthreads();

    // ---- issue next tile's gathers (hide under compute) ----
    const int tn = t + gx;
    if (tn < ntiles) {
#pragma unroll
      for (int i = 0; i < 4; ++i) {
        const int node = tn * NBM + i * 16 + r0;
        if (node < Nn) {
          const float* base = emb + (size_t)node * 128 + q * 8;
          p0[i] = *(const float4*)base;
          p1[i] = *(const float4*)(base + 4);
        }
      }
    }

    // ---- MFMA: h (biased) for all 4 m-chunks; per-row partial absmax ----
    f32x4 h0[4], h1[4];
#pragma unroll
    for (int m = 0; m < 4; ++m) {
      f32x4 acc0 = {0.f, 0.f, 0.f, 0.f};
      f32x4 acc1 = {0.f, 0.f, 0.f, 0.f};
      const int rowb = (m * 16 + l15) * 256;
      const int kb0  = lk8 * 2;
#pragma unroll
      for (int s = 0; s < 4; ++s) {
        const int off = rowb + ((s * 64 + kb0) ^ swz);
        const short8 a = *(const short8*)(Als + off);
        acc0 = __builtin_amdgcn_mfma_f32_16x16x32_bf16(a, bfrag[s][0], acc0, 0, 0, 0);
        acc1 = __builtin_amdgcn_mfma_f32_16x16x32_bf16(a, bfrag[s][1], acc1, 0, 0, 0);
      }
#pragma unroll
      for (int reg = 0; reg < 4; ++reg) {
        h0[m][reg] = acc0[reg] + bias0;
        h1[m][reg] = acc1[reg] + bias1;
        float pm = fmaxf(fabsf(h0[m][reg]), fabsf(h1[m][reg]));
        pm = fmaxf(pm, __shfl_xor(pm, 1, 16));
        pm = fmaxf(pm, __shfl_xor(pm, 2, 16));
        pm = fmaxf(pm, __shfl_xor(pm, 4, 16));
        pm = fmaxf(pm, __shfl_xor(pm, 8, 16));
        if (l15 == 0) pam[m * 16 + (lane >> 4) * 4 + reg][w] = pm;
      }
    }
    __syncthreads();

    // ---- quantize + store (2B packed per lane per row) ----
#pragma unroll
    for (int m = 0; m < 4; ++m) {
#pragma unroll
      for (int reg = 0; reg < 4; ++reg) {
        const int row  = m * 16 + (lane >> 4) * 4 + reg;
        const int node = t0 + row;
        const f32x4 pa = *(const f32x4*)pam[row];
        float am = fmaxf(fmaxf(pa[0], pa[1]), fmaxf(pa[2], pa[3]));
        am = fmaxf(am, 1e-20f);
        const float rq = 127.0f / am;
        if (node < Nn) {
          const int q0 = (int)rintf(h0[m][reg] * rq);
          const int q1 = (int)rintf(h1[m][reg] * rq);
          *(unsigned short*)(Qt + (size_t)node * 128 + colb) =
              (unsigned short)((q0 & 255) | ((q1 & 255) << 8));
          if ((tid & 15) == 0 && tid < 64)
            SCt[node] = am * (1.0f / 127.0f);
        }
      }
    }
    __syncthreads();
  }
}

// ============================================================================
// Phase 2: out[e] = sigmoid( sum_c relu(su*qu[c] + sv*qv[c]) * W2[c] + b2 )
// 16 lanes/edge, 8 int8 channels/lane (8B row-load, one L2 line per row).
// Scales via same-address broadcast loads from L2-resident tables.
// ============================================================================
__global__ __launch_bounds__(256, 8)
void edge_phase_q8(const int8_t* __restrict__ Qu,
                   const int8_t* __restrict__ Qv,
                   const float* __restrict__ scu,
                   const float* __restrict__ scv,
                   const int* __restrict__ eidx,
                   const float* __restrict__ W2,
                   const float* __restrict__ b2,
                   float* __restrict__ out,
                   int E) {
  const int tid = threadIdx.x;
  const int l15 = tid & 15;
  const int sg  = tid >> 4;

  float w2s[8];
#pragma unroll
  for (int j = 0; j < 8; ++j) w2s[j] = W2[l15 * 8 + j];
  const float b2s = b2[0];
  const int stride = gridDim.x * 16;

#pragma unroll 2
  for (int e = blockIdx.x * 16 + sg; e < E; e += stride) {
    const int s = eidx[e];
    const int d = eidx[E + e];
    const schar8 qu = *(const schar8*)(Qu + (size_t)s * 128 + l15 * 8);
    const schar8 qv = *(const schar8*)(Qv + (size_t)d * 128 + l15 * 8);
    const float su = scu[s];
    const float sv = scv[d];
    float acc = 0.f;
#pragma unroll
    for (int j = 0; j < 8; ++j) {
      float g = (float)(int)qu[j] * su + (float)(int)qv[j] * sv;
      g = g > 0.f ? g : 0.f;
      acc = fmaf(g, w2s[j], acc);
    }
    acc += __shfl_xor(acc, 1, 16);
    acc += __shfl_xor(acc, 2, 16);
    acc += __shfl_xor(acc, 4, 16);
    acc += __shfl_xor(acc, 8, 16);
    if (l15 == 0) out[e] = 1.f / (1.f + __expf(-(acc + b2s)));
  }
}

// ============================================================================
// Fallback (proven R2 kernel): fused gather+MFMA, used if ws_size too small.
// ============================================================================
#define BM 64
__global__ __launch_bounds__(256, 4)
void edge_decoder_fused(const float* __restrict__ src_emb,
                        const float* __restrict__ dst_emb,
                        const int* __restrict__ eidx,
                        const float* __restrict__ W1,
                        const float* __restrict__ b1,
                        const float* __restrict__ W2,
                        const float* __restrict__ b2,
                        float* __restrict__ out,
                        int E, int ntiles) {
  __shared__ __align__(16) char Als[BM * 512];
  __shared__ float rowpart[4][BM];

  const int tid  = threadIdx.x;
  const int lane = tid & 63;
  const int w    = tid >> 6;
  const int l15  = lane & 15;
  const int lk8  = (lane >> 4) * 8;

  short8 bfrag[8][2];
#pragma unroll
  for (int s = 0; s < 8; ++s) {
#pragma unroll
    for (int nf = 0; nf < 2; ++nf) {
      const int col = w * 32 + nf * 16 + l15;
      short8 t;
#pragma unroll
      for (int j = 0; j < 8; ++j) {
        const int k = s * 32 + lk8 + j;
        t[j] = (short)f2bf(W1[k * 128 + col]);
      }
      bfrag[s][nf] = t;
    }
  }
  float b1v[2], w2v[2];
#pragma unroll
  for (int nf = 0; nf < 2; ++nf) {
    const int col = w * 32 + nf * 16 + l15;
    b1v[nf] = b1[col];
    w2v[nf] = W2[col];
  }
  const float b2s = b2[0];

  const int q  = tid & 31;
  const int r0 = tid >> 5;
  const int qq = q & 15;
  const bool is_src = (q < 16);
  const int swz = (l15 & 7) << 4;

  for (int t = blockIdx.x; t < ntiles; t += gridDim.x) {
    const int t0 = t * BM;
#pragma unroll
    for (int i = 0; i < 8; ++i) {
      const int row = i * 8 + r0;
      const int e = t0 + row;
      if (e < E) {
        const int node = is_src ? eidx[e] : eidx[E + e];
        const float* base = (is_src ? src_emb : dst_emb) + (size_t)node * 128 + qq * 8;
        const float4 f0 = *(const float4*)base;
        const float4 f1 = *(const float4*)(base + 4);
        short8 hv;
        hv[0] = (short)f2bf(f0.x); hv[1] = (short)f2bf(f0.y);
        hv[2] = (short)f2bf(f0.z); hv[3] = (short)f2bf(f0.w);
        hv[4] = (short)f2bf(f1.x); hv[5] = (short)f2bf(f1.y);
        hv[6] = (short)f2bf(f1.z); hv[7] = (short)f2bf(f1.w);
        const int byteoff = row * 512 + ((q * 16) ^ ((row & 7) << 4));
        *(short8*)(Als + byteoff) = hv;
      }
    }
    __syncthreads();

    for (int m = 0; m < 4; ++m) {
      f32x4 acc0 = {0.f, 0.f, 0.f, 0.f};
      f32x4 acc1 = {0.f, 0.f, 0.f, 0.f};
      const int rowb = (m * 16 + l15) * 512;
      const int kb0  = lk8 * 2;
#pragma unroll
      for (int s = 0; s < 8; ++s) {
        const int off = rowb + ((s * 64 + kb0) ^ swz);
        const short8 a = *(const short8*)(Als + off);
        acc0 = __builtin_amdgcn_mfma_f32_16x16x32_bf16(a, bfrag[s][0], acc0, 0, 0, 0);
        acc1 = __builtin_amdgcn_mfma_f32_16x16x32_bf16(a, bfrag[s][1], acc1, 0, 0, 0);
      }
      float pr[4];
#pragma unroll
      for (int reg = 0; reg < 4; ++reg) {
        float h0 = acc0[reg] + b1v[0]; h0 = h0 > 0.f ? h0 : 0.f;
        float h1 = acc1[reg] + b1v[1]; h1 = h1 > 0.f ? h1 : 0.f;
        pr[reg] = h0 * w2v[0] + h1 * w2v[1];
      }
#pragma unroll
      for (int off = 1; off < 16; off <<= 1) {
#pragma unroll
        for (int reg = 0; reg < 4; ++reg)
          pr[reg] += __shfl_xor(pr[reg], off, 64);
      }
      if (l15 == 0) {
        const int rbase = m * 16 + (lane >> 4) * 4;
#pragma unroll
        for (int reg = 0; reg < 4; ++reg)
          rowpart[w][rbase + reg] = pr[reg];
      }
    }
    __syncthreads();

    if (tid < BM) {
      const int e = t0 + tid;
      if (e < E) {
        const float sum = rowpart[0][tid] + rowpart[1][tid] +
                          rowpart[2][tid] + rowpart[3][tid] + b2s;
        out[e] = 1.f / (1.f + __expf(-sum));
      }
    }
    __syncthreads();
  }
}

extern "C" void kernel_launch(void* const* d_in, const int* in_sizes, int n_in,
                              void* d_out, int out_size, void* d_ws, size_t ws_size,
                              hipStream_t stream) {
  const float* src = (const float*)d_in[0];
  const float* dst = (const float*)d_in[1];
  const int*   eix = (const int*)d_in[2];
  const float* W1  = (const float*)d_in[3];
  const float* b1  = (const float*)d_in[4];
  const float* W2  = (const float*)d_in[5];
  const float* b2  = (const float*)d_in[6];
  float* out = (float*)d_out;

  const int E  = in_sizes[2] / 2;
  const int Nn = in_sizes[0] / 128;
  // ws layout: Q (2 tables x Nn x 128 int8) | SC (2 tables x Nn f32)
  const size_t q_bytes  = (size_t)2 * Nn * 128;
  const size_t sc_bytes = (size_t)2 * Nn * sizeof(float);

  if (ws_size >= q_bytes + sc_bytes) {
    int8_t* Q  = (int8_t*)d_ws;
    float*  SC = (float*)((char*)d_ws + q_bytes);
    const int ntiles_n = (Nn + NBM - 1) / NBM;
    const int gx = ntiles_n < 512 ? ntiles_n : 512;
    node_phase_q8<<<dim3(gx, 2), 256, 0, stream>>>(src, dst, W1, b1, Q, SC, Nn, ntiles_n);
    const int nchunks = (E + 15) / 16;
    const int nblk = nchunks < 2048 ? nchunks : 2048;
    edge_phase_q8<<<nblk, 256, 0, stream>>>(Q, Q + (size_t)Nn * 128, SC, SC + Nn,
                                            eix, W2, b2, out, E);
  } else {
    const int ntiles = (E + BM - 1) / BM;
    const int grid = ntiles < 2048 ? ntiles : 2048;
    edge_decoder_fused<<<grid, 256, 0, stream>>>(src, dst, eix, W1, b1, W2, b2,
                                                 out, E, ntiles);
  }
}